// Round 2
// baseline (365.017 us; speedup 1.0000x reference)
//
#include <hip/hip_runtime.h>
#include <stdint.h>

#define FP8_MAX 448.0f
// Problem dims (fixed per setup_inputs): B=4, D=64, H=16, N=2048
#define NB 4
#define ND 64
#define NH 16
#define NS 2048

typedef float f32x4 __attribute__((ext_vector_type(4)));

// ---------------------------------------------------------------------------
// Pass 1: per-tensor abs-max.  First half of grid reduces q, second half k.
// Result stored as monotonic uint bits (valid max-order for non-negative f32).
// ---------------------------------------------------------------------------
__global__ __launch_bounds__(256) void amax_kernel(const float* __restrict__ q,
                                                   const float* __restrict__ k,
                                                   unsigned* __restrict__ amax,
                                                   int n4) {
  const int half = gridDim.x >> 1;
  const float4* src;
  unsigned* slot;
  int b;
  if ((int)blockIdx.x < half) { src = (const float4*)q; slot = amax;     b = blockIdx.x; }
  else                        { src = (const float4*)k; slot = amax + 1; b = blockIdx.x - half; }

  float m = 0.f;
  for (int i = b * 256 + threadIdx.x; i < n4; i += half * 256) {
    float4 v = src[i];
    m = fmaxf(m, fmaxf(fmaxf(fabsf(v.x), fabsf(v.y)), fmaxf(fabsf(v.z), fabsf(v.w))));
  }
#pragma unroll
  for (int off = 32; off > 0; off >>= 1)
    m = fmaxf(m, __shfl_xor(m, off, 64));

  __shared__ float red[4];
  if ((threadIdx.x & 63) == 0) red[threadIdx.x >> 6] = m;
  __syncthreads();
  if (threadIdx.x == 0) {
    m = fmaxf(fmaxf(red[0], red[1]), fmaxf(red[2], red[3]));
    atomicMax(slot, __float_as_uint(m));
  }
}

// ---------------------------------------------------------------------------
// Pass 2: quantize to fp8 e4m3 (RNE via v_cvt_pk_fp8_f32) AND repack into a
// fragment-packed layout for mfma_f32_16x16x32_fp8_fp8:
//   chunk index c = (((bh*128 + rg)*2 + ks)*64 + kg*16 + r16)  (8B chunks)
//   chunk holds d = ks*32 + kg*8 .. +7   of row n = rg*16 + r16
// A wave's fragment load in the GEMM is then chunk base + lane -> one
// perfectly coalesced 512B global_load_dwordx2 per fragment.
// Thread id == output chunk id -> fully contiguous 512B stores per wave.
// ---------------------------------------------------------------------------
__global__ __launch_bounds__(256) void quant_kernel(const float* __restrict__ in,
                                                    uint2* __restrict__ outp,
                                                    const unsigned* __restrict__ amaxbits) {
  const unsigned c = blockIdx.x * 256 + threadIdx.x;  // [0, 2^20)
  const float amax  = fmaxf(__uint_as_float(*amaxbits), 1e-12f);
  const float scale = FP8_MAX / amax;

  const unsigned r16 = c & 15;
  const unsigned kg  = (c >> 4) & 3;
  const unsigned ks  = (c >> 6) & 1;
  const unsigned rg  = (c >> 7) & 127;
  const unsigned bh  = c >> 14;
  const unsigned n   = rg * 16 + r16;
  const unsigned d0  = ks * 32 + kg * 8;
  const unsigned b   = bh >> 4, h = bh & 15;

  const float* src = in + (size_t)(b * ND + d0) * (NH * NS) + h * NS + n;

  float v[8];
#pragma unroll
  for (int j = 0; j < 8; ++j) {
    float x = src[(size_t)j * (NH * NS)] * scale;
    v[j] = fminf(fmaxf(x, -FP8_MAX), FP8_MAX);
  }
  unsigned lo = 0, hi = 0;
  lo = __builtin_amdgcn_cvt_pk_fp8_f32(v[0], v[1], lo, 0);
  lo = __builtin_amdgcn_cvt_pk_fp8_f32(v[2], v[3], lo, 1);
  hi = __builtin_amdgcn_cvt_pk_fp8_f32(v[4], v[5], hi, 0);
  hi = __builtin_amdgcn_cvt_pk_fp8_f32(v[6], v[7], hi, 1);
  outp[c] = make_uint2(lo, hi);
}

// ---------------------------------------------------------------------------
// Pass 3: batched GEMM  S[bh][n][m] = sum_d Q[bh][n][d] * K[bh][m][d]
// 128x128 tile per block, 4 waves (2x2, each 64x64 = 4x4 frags of 16x16).
// NO LDS: fragments load straight from the fragment-packed global layout
// (512B coalesced per wave-load; ~512MB total L2-level traffic).
// Operand swap: A-operand = K rows, B-operand = Q rows, so
//   D: row -> m (= kg*4 + reg, fast output dim), col -> n (= lane&15)
// giving float4 output stores (16 rows x 64B = 1KB per store instr).
// ---------------------------------------------------------------------------
__global__ __launch_bounds__(256) void gemm_kernel(const long long* __restrict__ qp,
                                                   const long long* __restrict__ kp,
                                                   float* __restrict__ out,
                                                   const unsigned* __restrict__ amaxbits) {
  const int tid  = threadIdx.x;
  const int lane = tid & 63;
  const int wid  = tid >> 6;
  const int wm   = wid >> 1;  // n-half (0..1)
  const int wn   = wid & 1;   // m-half (0..1)

  const int bh = blockIdx.z;
  const int n0 = blockIdx.y * 128;
  const int m0 = blockIdx.x * 128;

  const int r16 = lane & 15;
  const int kg  = lane >> 4;

  // fragment row-groups (16 rows each)
  const int rgq0 = (n0 >> 4) + wm * 4;  // Q row-group base for this wave
  const int rgk0 = (m0 >> 4) + wn * 4;  // K row-group base for this wave

  long long qfrag[2][4], kfrag[2][4];
#pragma unroll
  for (int ks = 0; ks < 2; ++ks) {
#pragma unroll
    for (int f = 0; f < 4; ++f) {
      qfrag[ks][f] = qp[((size_t)(bh * 128 + rgq0 + f) * 2 + ks) * 64 + lane];
      kfrag[ks][f] = kp[((size_t)(bh * 128 + rgk0 + f) * 2 + ks) * 64 + lane];
    }
  }

  f32x4 acc[4][4] = {};  // [i = m-frag][j = n-frag]
#pragma unroll
  for (int ks = 0; ks < 2; ++ks)
#pragma unroll
    for (int i = 0; i < 4; ++i)
#pragma unroll
      for (int j = 0; j < 4; ++j)
        acc[i][j] = __builtin_amdgcn_mfma_f32_16x16x32_fp8_fp8(kfrag[ks][i], qfrag[ks][j],
                                                               acc[i][j], 0, 0, 0);

  // dequant: S = (raw fp8 dot) * amax_q*amax_k/(448^2) / sqrt(64)
  const float aq = fmaxf(__uint_as_float(amaxbits[0]), 1e-12f);
  const float ak = fmaxf(__uint_as_float(amaxbits[1]), 1e-12f);
  const float dq = aq * ak / (FP8_MAX * FP8_MAX * 8.0f);

  float* outbh = out + (size_t)bh * NS * NS;
#pragma unroll
  for (int j = 0; j < 4; ++j) {
    const int n = n0 + wm * 64 + j * 16 + r16;
#pragma unroll
    for (int i = 0; i < 4; ++i) {
      const int m = m0 + wn * 64 + i * 16 + kg * 4;
      f32x4 v;
#pragma unroll
      for (int r = 0; r < 4; ++r) v[r] = acc[i][j][r] * dq;
      __builtin_nontemporal_store(v, (f32x4*)(outbh + (size_t)n * NS + m));
    }
  }
}

// ---------------------------------------------------------------------------
extern "C" void kernel_launch(void* const* d_in, const int* in_sizes, int n_in,
                              void* d_out, int out_size, void* d_ws, size_t ws_size,
                              hipStream_t stream) {
  const float* q = (const float*)d_in[0];
  const float* k = (const float*)d_in[1];
  float* out = (float*)d_out;

  // ws layout: [0..7] amax bits (q,k) | @256: fp8 Qp (8MB) | fp8 Kp (8MB)
  unsigned* amax = (unsigned*)d_ws;
  unsigned char* qp = (unsigned char*)d_ws + 256;
  unsigned char* kp = qp + (size_t)NB * NH * NS * ND;  // 8,388,608

  hipMemsetAsync(amax, 0, 8, stream);

  const int n4 = in_sizes[0] / 4;  // float4 count per tensor
  amax_kernel<<<1024, 256, 0, stream>>>(q, k, amax, n4);

  quant_kernel<<<4096, 256, 0, stream>>>(q, (uint2*)qp, amax);
  quant_kernel<<<4096, 256, 0, stream>>>(k, (uint2*)kp, amax + 1);

  dim3 grid(NS / 128, NS / 128, NB * NH);  // (m-tiles, n-tiles, bh)
  gemm_kernel<<<grid, 256, 0, stream>>>((const long long*)qp, (const long long*)kp, out, amax);
}

// Round 3
// 272.346 us; speedup vs baseline: 1.3403x; 1.3403x over previous
//
#include <hip/hip_runtime.h>
#include <stdint.h>

#define FP8_MAX 448.0f
// Problem dims (fixed per setup_inputs): B=4, D=64, H=16, N=2048
#define NB 4
#define ND 64
#define NH 16
#define NS 2048

typedef float f32x4 __attribute__((ext_vector_type(4)));

// ---------------------------------------------------------------------------
// Pass 1: per-tensor abs-max (ONE tensor per launch so the immediately
// following quant pass re-reads it out of the 256MB L3, not HBM).
// Result stored as monotonic uint bits (valid max-order for non-negative f32).
// ---------------------------------------------------------------------------
__global__ __launch_bounds__(256) void amax_kernel(const float* __restrict__ x,
                                                   unsigned* __restrict__ slot,
                                                   int n4) {
  const float4* src = (const float4*)x;
  float m = 0.f;
  for (int i = blockIdx.x * 256 + threadIdx.x; i < n4; i += gridDim.x * 256) {
    float4 v = src[i];
    m = fmaxf(m, fmaxf(fmaxf(fabsf(v.x), fabsf(v.y)), fmaxf(fabsf(v.z), fabsf(v.w))));
  }
#pragma unroll
  for (int off = 32; off > 0; off >>= 1)
    m = fmaxf(m, __shfl_xor(m, off, 64));

  __shared__ float red[4];
  if ((threadIdx.x & 63) == 0) red[threadIdx.x >> 6] = m;
  __syncthreads();
  if (threadIdx.x == 0) {
    m = fmaxf(fmaxf(red[0], red[1]), fmaxf(red[2], red[3]));
    atomicMax(slot, __float_as_uint(m));
  }
}

// ---------------------------------------------------------------------------
// Pass 2: quantize to fp8 e4m3 (RNE via v_cvt_pk_fp8_f32) AND repack into a
// fragment-packed layout for mfma_f32_16x16x32_fp8_fp8:
//   chunk index c = (((bh*128 + rg)*2 + ks)*64 + kg*16 + r16)  (8B chunks)
//   chunk holds d = ks*32 + kg*8 .. +7   of row n = rg*16 + r16
// Layout verified correct by R1/R2 passes. A 128-row tile is one contiguous
// 8KB region -> trivially coalesced staging in the GEMM.
// ---------------------------------------------------------------------------
__global__ __launch_bounds__(256) void quant_kernel(const float* __restrict__ in,
                                                    uint2* __restrict__ outp,
                                                    const unsigned* __restrict__ amaxbits) {
  const unsigned c = blockIdx.x * 256 + threadIdx.x;  // [0, 2^20)
  const float amax  = fmaxf(__uint_as_float(*amaxbits), 1e-12f);
  const float scale = FP8_MAX / amax;

  const unsigned r16 = c & 15;
  const unsigned kg  = (c >> 4) & 3;
  const unsigned ks  = (c >> 6) & 1;
  const unsigned rg  = (c >> 7) & 127;
  const unsigned bh  = c >> 14;
  const unsigned n   = rg * 16 + r16;
  const unsigned d0  = ks * 32 + kg * 8;
  const unsigned b   = bh >> 4, h = bh & 15;

  const float* src = in + (size_t)(b * ND + d0) * (NH * NS) + h * NS + n;

  float v[8];
#pragma unroll
  for (int j = 0; j < 8; ++j) {
    float x = src[(size_t)j * (NH * NS)] * scale;
    v[j] = fminf(fmaxf(x, -FP8_MAX), FP8_MAX);
  }
  unsigned lo = 0, hi = 0;
  lo = __builtin_amdgcn_cvt_pk_fp8_f32(v[0], v[1], lo, 0);
  lo = __builtin_amdgcn_cvt_pk_fp8_f32(v[2], v[3], lo, 1);
  hi = __builtin_amdgcn_cvt_pk_fp8_f32(v[4], v[5], hi, 0);
  hi = __builtin_amdgcn_cvt_pk_fp8_f32(v[6], v[7], hi, 1);
  outp[c] = make_uint2(lo, hi);
}

// ---------------------------------------------------------------------------
// Pass 3: batched GEMM  S[bh][n][m] = sum_d Q[bh][n][d] * K[bh][m][d]
// 128x128 tile per block, 4 waves (2x2, each 64x64 = 4x4 frags of 16x16).
// LDS-staged (each tile read ONCE from global: contiguous 8KB copy), with
// fragment-packed LDS layout so ds_read_b64 is lane-contiguous (2-way bank
// pattern = free).  Operand swap (A=K, B=Q) makes D's reg index walk m (the
// fast output dim) -> plain f32x4 stores, 64B segments, L2 write-combined.
// ---------------------------------------------------------------------------
__global__ __launch_bounds__(256) void gemm_kernel(const long long* __restrict__ qp,
                                                   const long long* __restrict__ kp,
                                                   float* __restrict__ out,
                                                   const unsigned* __restrict__ amaxbits) {
  __shared__ __align__(16) long long ldsA[1024];  // 8KB: 8 row-groups x 2 ks x 64 chunks
  __shared__ __align__(16) long long ldsB[1024];

  const int tid  = threadIdx.x;
  const int lane = tid & 63;
  const int wid  = tid >> 6;
  const int wm   = wid >> 1;  // n-half (0..1)
  const int wn   = wid & 1;   // m-half (0..1)

  const int bh = blockIdx.z;
  const int n0 = blockIdx.y * 128;
  const int m0 = blockIdx.x * 128;

  // Fragment-packed global tiles are contiguous: 8 row-groups * 128 chunks.
  const long long* Ag = qp + ((size_t)bh * 128 + (n0 >> 4)) * 128;
  const long long* Bg = kp + ((size_t)bh * 128 + (m0 >> 4)) * 128;

#pragma unroll
  for (int i = 0; i < 2; ++i) {
    int g = i * 512 + tid * 2;  // 16B per thread per iter
    *(uint4*)&ldsA[g] = *(const uint4*)&Ag[g];
    *(uint4*)&ldsB[g] = *(const uint4*)&Bg[g];
  }
  __syncthreads();

  const int r16 = lane & 15;
  const int kg  = lane >> 4;

  long long qfrag[2][4], kfrag[2][4];
#pragma unroll
  for (int ks = 0; ks < 2; ++ks) {
#pragma unroll
    for (int f = 0; f < 4; ++f) {
      qfrag[ks][f] = ldsA[((wm * 4 + f) * 2 + ks) * 64 + lane];
      kfrag[ks][f] = ldsB[((wn * 4 + f) * 2 + ks) * 64 + lane];
    }
  }

  f32x4 acc[4][4] = {};  // [i = m-frag][j = n-frag]
#pragma unroll
  for (int ks = 0; ks < 2; ++ks)
#pragma unroll
    for (int i = 0; i < 4; ++i)
#pragma unroll
      for (int j = 0; j < 4; ++j)
        acc[i][j] = __builtin_amdgcn_mfma_f32_16x16x32_fp8_fp8(kfrag[ks][i], qfrag[ks][j],
                                                               acc[i][j], 0, 0, 0);

  // dequant: S = (raw fp8 dot) * amax_q*amax_k/(448^2) / sqrt(64)
  const float aq = fmaxf(__uint_as_float(amaxbits[0]), 1e-12f);
  const float ak = fmaxf(__uint_as_float(amaxbits[1]), 1e-12f);
  const float dq = aq * ak / (FP8_MAX * FP8_MAX * 8.0f);

  float* outbh = out + (size_t)bh * NS * NS;
#pragma unroll
  for (int j = 0; j < 4; ++j) {
    const int n = n0 + wm * 64 + j * 16 + r16;
#pragma unroll
    for (int i = 0; i < 4; ++i) {
      const int m = m0 + wn * 64 + i * 16 + kg * 4;
      f32x4 v;
#pragma unroll
      for (int r = 0; r < 4; ++r) v[r] = acc[i][j][r] * dq;
      *(f32x4*)(outbh + (size_t)n * NS + m) = v;
    }
  }
}

// ---------------------------------------------------------------------------
extern "C" void kernel_launch(void* const* d_in, const int* in_sizes, int n_in,
                              void* d_out, int out_size, void* d_ws, size_t ws_size,
                              hipStream_t stream) {
  const float* q = (const float*)d_in[0];
  const float* k = (const float*)d_in[1];
  float* out = (float*)d_out;

  // ws layout: [0..7] amax bits (q,k) | @256: fp8 Qp (8MB) | fp8 Kp (8MB)
  unsigned* amax = (unsigned*)d_ws;
  unsigned char* qp = (unsigned char*)d_ws + 256;
  unsigned char* kp = qp + (size_t)NB * NH * NS * ND;  // 8,388,608

  hipMemsetAsync(amax, 0, 8, stream);

  const int n4 = in_sizes[0] / 4;  // float4 count per tensor

  // Per-tensor ordering: quant_X immediately follows amax_X so the 134MB
  // tensor is still L3-resident (256MB) for the re-read.
  amax_kernel<<<1024, 256, 0, stream>>>(q, amax, n4);
  quant_kernel<<<4096, 256, 0, stream>>>(q, (uint2*)qp, amax);
  amax_kernel<<<1024, 256, 0, stream>>>(k, amax + 1, n4);
  quant_kernel<<<4096, 256, 0, stream>>>(k, (uint2*)kp, amax + 1);

  dim3 grid(NS / 128, NS / 128, NB * NH);  // (m-tiles, n-tiles, bh)
  gemm_kernel<<<grid, 256, 0, stream>>>((const long long*)qp, (const long long*)kp, out, amax);
}